// Round 7
// baseline (444.223 us; speedup 1.0000x reference)
//
#include <hip/hip_runtime.h>
#include <hip/hip_bf16.h>

// BPNN: B=512, N=2048, F=64, T=4, H1=64, H2=32.
// out[b] = sum_n MLP_{t[n]}(x[b,n,:]), MLP = silu(W0 x+b0) -> silu(W1 h+b1) -> w2.h+b2
//
// R9 (resubmit; round 6 was an infra failure, kernel never ran).
// Sequential-HBM restructure.
//  Evidence: R6 (2-deep reg prefetch), R7 (1-wave blocks), R8 (3-deep DMA ring,
//  counted vmcnt) all land at ~120us = 2.2 TB/s. All three share one property:
//  every x access touches 128B lines strided 512KB apart (16 b-rows/wave).
//  That pattern is DRAM row-activate bound (~35% efficiency); the harness's own
//  contiguous 1-GiB fill hits 6.7 TB/s on the same HBM. Fix the ADDRESSES:
//  - stage x in natural n-order: per b-row, global_load_lds of 2KB contiguous
//    per chunk; each row is a sequential 16KB stream across the block.
//  - double-buffered 8-atom chunk (2 x 16 x 2064B, +16B row pad for LDS banks);
//    2-phase: stage c+1 -> compute c -> __syncthreads (vmcnt(0) drain by
//    compiler = proven minimal T3 pattern).
//  - type handling: ballot-sort each 8-atom tile in-register; wave w takes
//    sorted positions {2w, 2w+1} -> balanced, quasi-static type per wave
//    (~1 frag reload), no global sort prepass.
//  Compute path (frags/MFMA/silu/trb) identical to R8.
// MFMA orientation: D = W * x^T (A-frag == B-frag lane mapping, verified R2).

#define B_ 512
#define N_ 2048
#define F_ 64
#define T_ 4
#define H1_ 64
#define H2_ 32

#define BT 16            // b-tile (MFMA N dim)
#define WAVES 4
#define NC 8             // atoms per staged chunk
#define NTILE 8          // chunks per block
#define NCHUNK (NC * NTILE)   // 64 atoms per block
#define ROWPAD 2064      // NC*256 + 16 pad (spreads ds_read bank starts)

typedef __attribute__((ext_vector_type(8))) short bf16x8;
typedef __attribute__((ext_vector_type(4))) short bf16x4;
typedef __attribute__((ext_vector_type(4))) float f32x4;

typedef const __attribute__((address_space(1))) void* gas_ptr;
typedef __attribute__((address_space(3))) void* las_ptr;

__device__ inline float silu_f(float v) {
    return v * __builtin_amdgcn_rcpf(1.0f + __expf(-v));
}

__device__ inline bf16x8 pack8(float4 a, float4 b) {
    union { __hip_bfloat162 h[4]; bf16x8 v; } u;
    u.h[0] = __float22bfloat162_rn({a.x, a.y});
    u.h[1] = __float22bfloat162_rn({a.z, a.w});
    u.h[2] = __float22bfloat162_rn({b.x, b.y});
    u.h[3] = __float22bfloat162_rn({b.z, b.w});
    return u.v;
}

__device__ inline bf16x4 pack4(float a, float b, float c, float d) {
    union { __hip_bfloat162 h[2]; bf16x4 v; } u;
    u.h[0] = __float22bfloat162_rn({a, b});
    u.h[1] = __float22bfloat162_rn({c, d});
    return u.v;
}

__device__ inline float bf_at(bf16x4 v, int r) {
    union { bf16x4 v; __hip_bfloat16 h[4]; } u; u.v = v;
    return __bfloat162float(u.h[r]);
}

__global__ __launch_bounds__(256) void bpnn_kernel(
    const float* __restrict__ x, const int* __restrict__ an,
    const float* __restrict__ w0, const float* __restrict__ b0,
    const float* __restrict__ w1, const float* __restrict__ b1,
    const float* __restrict__ w2, const float* __restrict__ b2,
    float* __restrict__ out)
{
    __shared__ __align__(16) char xbuf[2][BT * ROWPAD];         // 66048 B
    __shared__ __align__(16) __hip_bfloat16 trb[WAVES][BT][68]; // 8704 B
    __shared__ int sidx[NCHUNK];                                // 256 B

    const int tid  = threadIdx.x;
    const int wave = tid >> 6;
    const int lane = tid & 63;
    const int lr   = lane & 15;      // b-col (B,C) / row (A)
    const int q    = lane >> 4;      // quad
    const int b0i  = blockIdx.y * BT;
    const int n0   = blockIdx.x * NCHUNK;

    // ---- ballot-sort each 8-atom tile by type (tile g = lane>>3) ----
    {
        const int t = an[n0 + lane];
        unsigned long long m0 = __ballot(t == 0);
        unsigned long long m1 = __ballot(t == 1);
        unsigned long long m2 = __ballot(t == 2);
        unsigned long long m3 = __ballot(t == 3);
        const int g = lane >> 3, j = lane & 7;
        const unsigned gm0 = (unsigned)(m0 >> (g * 8)) & 0xFFu;
        const unsigned gm1 = (unsigned)(m1 >> (g * 8)) & 0xFFu;
        const unsigned gm2 = (unsigned)(m2 >> (g * 8)) & 0xFFu;
        const unsigned gm3 = (unsigned)(m3 >> (g * 8)) & 0xFFu;
        const unsigned gmt = (t == 0) ? gm0 : (t == 1) ? gm1 : (t == 2) ? gm2 : gm3;
        int below = 0;
        if (t > 0) below += (int)__popc(gm0);
        if (t > 1) below += (int)__popc(gm1);
        if (t > 2) below += (int)__popc(gm2);
        const int pos = (g << 3) + below + (int)__popc(gmt & ((1u << j) - 1u));
        if (wave == 0) sidx[pos] = (t << 8) | j;   // j = n-local within tile
    }

    // ---- DMA stage: wave w stages rows 4w..4w+3; per row 2x1KB contiguous ----
    const char* xB = (const char*)x;
    auto stage = [&](int pb, int c) {
#pragma unroll
        for (int rr = 0; rr < 4; ++rr) {
            const int rw = (wave << 2) + rr;
            const char* g = xB
                + ((size_t)(b0i + rw) * (N_ * F_) + (size_t)(n0 + c * NC) * F_) * 4
                + (size_t)lane * 16;
            char* l = &xbuf[pb][rw * ROWPAD];
            __builtin_amdgcn_global_load_lds((gas_ptr)g,          (las_ptr)l,          16, 0, 0);
            __builtin_amdgcn_global_load_lds((gas_ptr)(g + 1024), (las_ptr)(l + 1024), 16, 0, 0);
        }
    };

    stage(0, 0);
    __syncthreads();                 // compiler drains vmcnt(0); sidx visible
    const int myid = sidx[lane];     // lane L holds sorted slot L (tile L>>3)

    float esum0 = 0.f, esum1 = 0.f, bsum = 0.f;

    // fragment registers: individually named -> guaranteed registers
    bf16x8 aw000, aw001, aw010, aw011, aw020, aw021, aw030, aw031;
    bf16x8 aw100, aw101, aw110, aw111;
    bf16x4 b0f0, b0f1, b0f2, b0f3, b1f0, b1f1, w2f0, w2f1;
    float b2c = 0.f;
    int cur_t = -1;

    __hip_bfloat16* trbw = &trb[wave][lr][0];

#pragma unroll 1
    for (int c = 0; c < NTILE; ++c) {
        const int pb = c & 1;
        if (c + 1 < NTILE) stage(pb ^ 1, c + 1);   // fire-and-forget next chunk

#pragma unroll
        for (int jj = 0; jj < 2; ++jj) {
            const int id = __builtin_amdgcn_readlane(myid, (c << 3) + (wave << 1) + jj);
            const int t    = id >> 8;
            const int nloc = id & 0xFF;
            if (t != cur_t) {        // rare: quasi-static type per wave
                cur_t = t;
                const float* wb = w0 + t * (H1_ * F_) + lr * F_ + q * 8;
                const float4* pw;
                pw = reinterpret_cast<const float4*>(wb +  0 * F_ +  0); aw000 = pack8(pw[0], pw[1]);
                pw = reinterpret_cast<const float4*>(wb +  0 * F_ + 32); aw001 = pack8(pw[0], pw[1]);
                pw = reinterpret_cast<const float4*>(wb + 16 * F_ +  0); aw010 = pack8(pw[0], pw[1]);
                pw = reinterpret_cast<const float4*>(wb + 16 * F_ + 32); aw011 = pack8(pw[0], pw[1]);
                pw = reinterpret_cast<const float4*>(wb + 32 * F_ +  0); aw020 = pack8(pw[0], pw[1]);
                pw = reinterpret_cast<const float4*>(wb + 32 * F_ + 32); aw021 = pack8(pw[0], pw[1]);
                pw = reinterpret_cast<const float4*>(wb + 48 * F_ +  0); aw030 = pack8(pw[0], pw[1]);
                pw = reinterpret_cast<const float4*>(wb + 48 * F_ + 32); aw031 = pack8(pw[0], pw[1]);
                const float* wc = w1 + t * (H2_ * H1_) + lr * H1_ + q * 8;
                pw = reinterpret_cast<const float4*>(wc +  0 * H1_ +  0); aw100 = pack8(pw[0], pw[1]);
                pw = reinterpret_cast<const float4*>(wc +  0 * H1_ + 32); aw101 = pack8(pw[0], pw[1]);
                pw = reinterpret_cast<const float4*>(wc + 16 * H1_ +  0); aw110 = pack8(pw[0], pw[1]);
                pw = reinterpret_cast<const float4*>(wc + 16 * H1_ + 32); aw111 = pack8(pw[0], pw[1]);
                float4 v;
                v = *reinterpret_cast<const float4*>(b0 + t * H1_ +  0 + q * 4); b0f0 = pack4(v.x, v.y, v.z, v.w);
                v = *reinterpret_cast<const float4*>(b0 + t * H1_ + 16 + q * 4); b0f1 = pack4(v.x, v.y, v.z, v.w);
                v = *reinterpret_cast<const float4*>(b0 + t * H1_ + 32 + q * 4); b0f2 = pack4(v.x, v.y, v.z, v.w);
                v = *reinterpret_cast<const float4*>(b0 + t * H1_ + 48 + q * 4); b0f3 = pack4(v.x, v.y, v.z, v.w);
                v = *reinterpret_cast<const float4*>(b1 + t * H2_ +  0 + q * 4); b1f0 = pack4(v.x, v.y, v.z, v.w);
                v = *reinterpret_cast<const float4*>(b1 + t * H2_ + 16 + q * 4); b1f1 = pack4(v.x, v.y, v.z, v.w);
                v = *reinterpret_cast<const float4*>(w2 + t * H2_ +  0 + q * 4); w2f0 = pack4(v.x, v.y, v.z, v.w);
                v = *reinterpret_cast<const float4*>(w2 + t * H2_ + 16 + q * 4); w2f1 = pack4(v.x, v.y, v.z, v.w);
                b2c = b2[t];
            }

            // ---- x fragment from staged chunk (LDS transpose read) ----
            const char* rb = &xbuf[pb][lr * ROWPAD + nloc * 256 + q * 32];
            float4 f0 = *reinterpret_cast<const float4*>(rb);
            float4 f1 = *reinterpret_cast<const float4*>(rb + 16);
            float4 f2 = *reinterpret_cast<const float4*>(rb + 128);
            float4 f3 = *reinterpret_cast<const float4*>(rb + 144);

            bf16x8 xf0 = pack8(f0, f1);
            bf16x8 xf1 = pack8(f2, f3);
            bsum += b2c;

            // ---- layer 0: D0[64h x 16b] = W0_t * x^T ----
            f32x4 acc0 = {0.f,0.f,0.f,0.f}, acc1 = {0.f,0.f,0.f,0.f};
            f32x4 acc2 = {0.f,0.f,0.f,0.f}, acc3 = {0.f,0.f,0.f,0.f};
            acc0 = __builtin_amdgcn_mfma_f32_16x16x32_bf16(aw000, xf0, acc0, 0, 0, 0);
            acc0 = __builtin_amdgcn_mfma_f32_16x16x32_bf16(aw001, xf1, acc0, 0, 0, 0);
            acc1 = __builtin_amdgcn_mfma_f32_16x16x32_bf16(aw010, xf0, acc1, 0, 0, 0);
            acc1 = __builtin_amdgcn_mfma_f32_16x16x32_bf16(aw011, xf1, acc1, 0, 0, 0);
            acc2 = __builtin_amdgcn_mfma_f32_16x16x32_bf16(aw020, xf0, acc2, 0, 0, 0);
            acc2 = __builtin_amdgcn_mfma_f32_16x16x32_bf16(aw021, xf1, acc2, 0, 0, 0);
            acc3 = __builtin_amdgcn_mfma_f32_16x16x32_bf16(aw030, xf0, acc3, 0, 0, 0);
            acc3 = __builtin_amdgcn_mfma_f32_16x16x32_bf16(aw031, xf1, acc3, 0, 0, 0);

            // bias + silu; lane holds h = nt*16 + q*4 + r, b = lr
            {
                float v0 = silu_f(acc0[0] + bf_at(b0f0, 0));
                float v1 = silu_f(acc0[1] + bf_at(b0f0, 1));
                float v2 = silu_f(acc0[2] + bf_at(b0f0, 2));
                float v3 = silu_f(acc0[3] + bf_at(b0f0, 3));
                *reinterpret_cast<bf16x4*>(trbw +  0 + q * 4) = pack4(v0, v1, v2, v3);
                v0 = silu_f(acc1[0] + bf_at(b0f1, 0));
                v1 = silu_f(acc1[1] + bf_at(b0f1, 1));
                v2 = silu_f(acc1[2] + bf_at(b0f1, 2));
                v3 = silu_f(acc1[3] + bf_at(b0f1, 3));
                *reinterpret_cast<bf16x4*>(trbw + 16 + q * 4) = pack4(v0, v1, v2, v3);
                v0 = silu_f(acc2[0] + bf_at(b0f2, 0));
                v1 = silu_f(acc2[1] + bf_at(b0f2, 1));
                v2 = silu_f(acc2[2] + bf_at(b0f2, 2));
                v3 = silu_f(acc2[3] + bf_at(b0f2, 3));
                *reinterpret_cast<bf16x4*>(trbw + 32 + q * 4) = pack4(v0, v1, v2, v3);
                v0 = silu_f(acc3[0] + bf_at(b0f3, 0));
                v1 = silu_f(acc3[1] + bf_at(b0f3, 1));
                v2 = silu_f(acc3[2] + bf_at(b0f3, 2));
                v3 = silu_f(acc3[3] + bf_at(b0f3, 3));
                *reinterpret_cast<bf16x4*>(trbw + 48 + q * 4) = pack4(v0, v1, v2, v3);
            }
            __builtin_amdgcn_wave_barrier();  // order LDS write->read (per-wave buffer)

            bf16x8 hb0 = *reinterpret_cast<const bf16x8*>(trbw + q * 8);
            bf16x8 hb1 = *reinterpret_cast<const bf16x8*>(trbw + 32 + q * 8);
            __builtin_amdgcn_wave_barrier();

            // ---- layer 1: D1[32g x 16b] = W1_t * h1 ----
            f32x4 acB0 = {0.f,0.f,0.f,0.f}, acB1 = {0.f,0.f,0.f,0.f};
            acB0 = __builtin_amdgcn_mfma_f32_16x16x32_bf16(aw100, hb0, acB0, 0, 0, 0);
            acB0 = __builtin_amdgcn_mfma_f32_16x16x32_bf16(aw101, hb1, acB0, 0, 0, 0);
            acB1 = __builtin_amdgcn_mfma_f32_16x16x32_bf16(aw110, hb0, acB1, 0, 0, 0);
            acB1 = __builtin_amdgcn_mfma_f32_16x16x32_bf16(aw111, hb1, acB1, 0, 0, 0);

            // ---- layer 2: lane accumulates w2[g]*silu(.) over its 8 g ----
#pragma unroll
            for (int r = 0; r < 4; ++r) {
                esum0 += silu_f(acB0[r] + bf_at(b1f0, r)) * bf_at(w2f0, r);
                esum1 += silu_f(acB1[r] + bf_at(b1f1, r)) * bf_at(w2f1, r);
            }
        }

        __syncthreads();   // chunk boundary: my ds_reads done + next stage landed
    }

    // reduce esum over the 4 quads holding the same b (lane bits 4-5)
    float esum = esum0 + esum1;
    esum += __shfl_xor(esum, 16);
    esum += __shfl_xor(esum, 32);
    if (q == 0) atomicAdd(&out[b0i + lr], esum + bsum);  // bsum wave-uniform: add once
}

extern "C" void kernel_launch(void* const* d_in, const int* in_sizes, int n_in,
                              void* d_out, int out_size, void* d_ws, size_t ws_size,
                              hipStream_t stream) {
    const float* x  = (const float*)d_in[0];
    const int*   an = (const int*)d_in[1];
    const float* w0 = (const float*)d_in[2];
    const float* b0 = (const float*)d_in[3];
    const float* w1 = (const float*)d_in[4];
    const float* b1 = (const float*)d_in[5];
    const float* w2 = (const float*)d_in[6];
    const float* b2 = (const float*)d_in[7];
    float* out = (float*)d_out;

    hipMemsetAsync(out, 0, B_ * sizeof(float), stream);   // out accumulated via atomics
    dim3 grid(N_ / NCHUNK, B_ / BT);                      // (32, 32) = 1024 blocks
    bpnn_kernel<<<grid, 256, 0, stream>>>(x, an, w0, b0, w1, b1, w2, b2, out);
}